// Round 5
// baseline (220.584 us; speedup 1.0000x reference)
//
#include <hip/hip_runtime.h>
#include <hip/hip_bf16.h>
#include <math.h>

// Problem constants (MultiheadAttention: B=2, N=2048, E=1024, H=16, hd=64)
#define EDIM 1024
#define N3E  3072
#define NSEQ 2048
#define NB   2
#define NH   16
#define HD   64
#define MTOT (NB*NSEQ)   // 4096

typedef __attribute__((ext_vector_type(8))) short bf16x8;
typedef __attribute__((ext_vector_type(4))) float f32x4;

#define SCALE2 0.360673760222241f   // 0.25 * log2(e)
#define DTHR   16.0f                // defer-max threshold (raw-score units; P <= 2^5.8)

__device__ __forceinline__ short f2bf(float f) {
    union { float f; unsigned u; } v; v.f = f;
    unsigned r = v.u + 0x7FFFu + ((v.u >> 16) & 1u);   // RNE
    return (short)(r >> 16);
}

__device__ __forceinline__ unsigned cvtpk(float lo, float hi) {
    unsigned r;
    asm("v_cvt_pk_bf16_f32 %0, %1, %2" : "=v"(r) : "v"(lo), "v"(hi));
    return r;
}

__device__ __forceinline__ void gload16(const void* g, void* l) {
    __builtin_amdgcn_global_load_lds(
        (const __attribute__((address_space(1))) unsigned int*)g,
        (__attribute__((address_space(3))) unsigned int*)l, 16, 0, 0);
}

// ---------- prep 1: x fp32 -> bf16 ----------
__global__ __launch_bounds__(256) void k_convert_x(const float* __restrict__ x,
                                                   short* __restrict__ xb, int n4) {
    int i = blockIdx.x * blockDim.x + threadIdx.x;
    int stride = gridDim.x * blockDim.x;
    for (; i < n4; i += stride) {
        float4 v = ((const float4*)x)[i];
        ushort4 o;
        o.x = (unsigned short)f2bf(v.x);
        o.y = (unsigned short)f2bf(v.y);
        o.z = (unsigned short)f2bf(v.z);
        o.w = (unsigned short)f2bf(v.w);
        ((ushort4*)xb)[i] = o;
    }
}

// ---------- prep 2: W[k][c] fp32 -> Wt[c'][k] bf16 ----------
// actual col c = (e*16+h)*3 + qkv ; logical c' = qkv*1024 + h*64 + e
__global__ __launch_bounds__(256) void k_transpose_w(const float* __restrict__ w,
                                                     short* __restrict__ wt) {
    __shared__ float T[96][68];
    int k0 = blockIdx.x * 64;
    int c0 = blockIdx.y * 96;
    int t = threadIdx.x;
    {
        int kr = t >> 2;
        int cb = (t & 3) * 24;
        const float* src = w + (size_t)(k0 + kr) * N3E + c0 + cb;
        #pragma unroll
        for (int i = 0; i < 24; i += 4) {
            float4 v = *(const float4*)(src + i);
            T[cb + i + 0][kr] = v.x;
            T[cb + i + 1][kr] = v.y;
            T[cb + i + 2][kr] = v.z;
            T[cb + i + 3][kr] = v.w;
        }
    }
    __syncthreads();
    int kk = (t & 7) * 8;
    #pragma unroll
    for (int p = 0; p < 3; ++p) {
        int cc = p * 32 + (t >> 3);
        int ca = c0 + cc;
        int e = ca / 48, h = (ca % 48) / 3, q = ca % 3;
        int cp = q * 1024 + h * 64 + e;
        bf16x8 o;
        #pragma unroll
        for (int j = 0; j < 8; ++j) o[j] = f2bf(T[cc][kk + j]);
        *(bf16x8*)(wt + (size_t)cp * EDIM + k0 + kk) = o;
    }
}

// ---------- prep 3: bias permute ----------
__global__ void k_perm_bias(const float* __restrict__ b, float* __restrict__ bp) {
    int c = blockIdx.x * 256 + threadIdx.x;
    if (c >= N3E) return;
    int e = c / 48, h = (c % 48) / 3, q = c % 3;
    bp[q * 1024 + h * 64 + e] = b[c];
}

// ---------- QKV GEMM: 2-phase dbuf + global_load_lds(16B) + XCD swizzle ----------
__global__ __launch_bounds__(256) void k_qkv_gemm(const short* __restrict__ xb,
        const short* __restrict__ wt, const float* __restrict__ bp,
        short* __restrict__ qkv) {
    __shared__ short Al[2][128][32];
    __shared__ short Bl[2][128][32];
    int t = threadIdx.x, lane = t & 63, wv = t >> 6;
    int g = lane >> 4, r = lane & 15;
    int wr = wv >> 1, wc = wv & 1;
    // XCD-chunked swizzle: 768 blocks = 8 XCDs x 96; same-XCD keeps same n-panel
    int flat = blockIdx.y * 32 + blockIdx.x;
    int sw = (flat & 7) * 96 + (flat >> 3);
    int m0 = (sw & 31) * 128, n0 = (sw >> 5) * 128;
    // staging: 1KB chunk per (wave, j); row = wv*32 + j*16 + lane/4, col = (lane&3)*8
    int srow = wv * 32 + (lane >> 2);
    int scol = (lane & 3) * 8;
    const short* ga0 = xb + (size_t)(m0 + srow) * EDIM + scol;
    const short* ga1 = ga0 + (size_t)16 * EDIM;
    const short* gb0 = wt + (size_t)(n0 + srow) * EDIM + scol;
    const short* gb1 = gb0 + (size_t)16 * EDIM;
    char* laA = (char*)(&Al[0][0][0]) + wv * 2048;
    char* laB = (char*)(&Bl[0][0][0]) + wv * 2048;
    f32x4 acc[4][4] = {};
    // prologue: stage K-step 0 into buf 0
    gload16(ga0, laA);
    gload16(ga1, laA + 1024);
    gload16(gb0, laB);
    gload16(gb1, laB + 1024);
    __syncthreads();
    for (int step = 0; step < 32; ++step) {
        if (step < 31) {   // issue next K-step into the other buffer BEFORE compute
            int nk = (step + 1) * 32;
            int bo = ((step + 1) & 1) * 8192;
            gload16(ga0 + nk, laA + bo);
            gload16(ga1 + nk, laA + bo + 1024);
            gload16(gb0 + nk, laB + bo);
            gload16(gb1 + nk, laB + bo + 1024);
        }
        int cb = step & 1;
        bf16x8 af[4], bfr[4];
        #pragma unroll
        for (int mt = 0; mt < 4; ++mt)
            af[mt] = *(const bf16x8*)(&Al[cb][wr*64 + mt*16 + r][g*8]);
        #pragma unroll
        for (int nt = 0; nt < 4; ++nt)
            bfr[nt] = *(const bf16x8*)(&Bl[cb][wc*64 + nt*16 + r][g*8]);
        #pragma unroll
        for (int mt = 0; mt < 4; ++mt)
            #pragma unroll
            for (int nt = 0; nt < 4; ++nt)
                acc[mt][nt] = __builtin_amdgcn_mfma_f32_16x16x32_bf16(
                                  af[mt], bfr[nt], acc[mt][nt], 0, 0, 0);
        __syncthreads();   // drains vmcnt(0): next-buf loads had the MFMA phase to land
    }
    #pragma unroll
    for (int nt = 0; nt < 4; ++nt) {
        int cp = n0 + wc*64 + nt*16 + r;
        float bias = bp[cp];
        int q = cp >> 10, h = (cp >> 6) & 15, e = cp & 63;
        #pragma unroll
        for (int mt = 0; mt < 4; ++mt) {
            #pragma unroll
            for (int rg = 0; rg < 4; ++rg) {
                int m = m0 + wr*64 + mt*16 + g*4 + rg;
                int bb = m >> 11, n = m & 2047;
                qkv[((((size_t)q*NB + bb)*NH + h)*NSEQ + n)*HD + e] =
                    f2bf(acc[mt][nt][rg] + bias);
            }
        }
    }
}

// ---------- flash attention: 64 q/block (wave=16 rows), lane-local softmax ----------
// grid (32 qblocks, 16 heads, 2 batch) = 1024 blocks -> 4 blocks/CU, 16 waves/CU.
// S^T = mfma(K,Q): lane (g,r) holds S[q=r][kv=16jt+4g+rg]; defer-max (T13).
__global__ __launch_bounds__(256) void k_attn(const short* __restrict__ qkv,
                                              float* __restrict__ out) {
    __shared__ short Kl[64][68];      // 68-pad: staging + frag reads bank-balanced
    __shared__ short Vt[64][68];      // [d][kv]
    __shared__ short Pl[4][16][64];   // per-wave, XOR-swizzled rows
    int t = threadIdx.x, lane = t & 63, wv = t >> 6;
    int g = lane >> 4, r = lane & 15;
    int qb = blockIdx.x, h = blockIdx.y, b = blockIdx.z;
    const size_t HS = (size_t)NSEQ * HD;
    const short* Qp = qkv + ((size_t)(0*NB + b)*NH + h) * HS;
    const short* Kp = qkv + ((size_t)(1*NB + b)*NH + h) * HS;
    const short* Vp = qkv + ((size_t)(2*NB + b)*NH + h) * HS;
    int q0 = qb * 64 + wv * 16;
    bf16x8 qf0 = *(const bf16x8*)(Qp + (size_t)(q0 + r)*HD + g*8);
    bf16x8 qf1 = *(const bf16x8*)(Qp + (size_t)(q0 + r)*HD + 32 + g*8);
    f32x4 o[4] = {};
    float mr = -3.0e38f, lr = 0.f;
    int skv = t >> 2, sd = (t & 3) * 16;          // K staging
    int vkv = (t >> 4) * 4, vd = (t & 15) * 4;    // V staging (4kv x 4d / lane)
    int rx = (r & 7) << 4;                        // P swizzle
    char* prow = (char*)(&Pl[wv][0][0]) + r * 128;
    bf16x8 kk0, kk1; ushort4 vv0, vv1, vv2, vv3;
    const short* Kst = Kp + (size_t)skv * HD + sd;
    const short* Vst = Vp + (size_t)vkv * HD + vd;
    kk0 = *(const bf16x8*)(Kst);
    kk1 = *(const bf16x8*)(Kst + 8);
    vv0 = *(const ushort4*)(Vst);
    vv1 = *(const ushort4*)(Vst + HD);
    vv2 = *(const ushort4*)(Vst + 2*HD);
    vv3 = *(const ushort4*)(Vst + 3*HD);
    {
        *(bf16x8*)(&Kl[skv][sd]) = kk0;
        *(bf16x8*)(&Kl[skv][sd + 8]) = kk1;
        #pragma unroll
        for (int i = 0; i < 4; ++i) {
            unsigned lo = (unsigned)((const unsigned short*)&vv0)[i]
                        | ((unsigned)((const unsigned short*)&vv1)[i] << 16);
            unsigned hi = (unsigned)((const unsigned short*)&vv2)[i]
                        | ((unsigned)((const unsigned short*)&vv3)[i] << 16);
            uint2 wrd; wrd.x = lo; wrd.y = hi;
            *(uint2*)(&Vt[vd + i][vkv]) = wrd;
        }
    }
    for (int kt = 0; kt < NSEQ; kt += 64) {
        __syncthreads();
        bool more = (kt + 64) < NSEQ;
        if (more) {   // T14: issue next tile's global loads before compute
            kk0 = *(const bf16x8*)(Kst + (size_t)(kt + 64) * HD);
            kk1 = *(const bf16x8*)(Kst + (size_t)(kt + 64) * HD + 8);
            vv0 = *(const ushort4*)(Vst + (size_t)(kt + 64) * HD);
            vv1 = *(const ushort4*)(Vst + (size_t)(kt + 65) * HD);
            vv2 = *(const ushort4*)(Vst + (size_t)(kt + 66) * HD);
            vv3 = *(const ushort4*)(Vst + (size_t)(kt + 67) * HD);
        }
        // ---- QK^T (swapped)
        f32x4 s[4];
        #pragma unroll
        for (int jt = 0; jt < 4; ++jt) {
            bf16x8 kf0 = *(const bf16x8*)(&Kl[jt*16 + r][g*8]);
            bf16x8 kf1 = *(const bf16x8*)(&Kl[jt*16 + r][32 + g*8]);
            f32x4 z = {};
            s[jt] = __builtin_amdgcn_mfma_f32_16x16x32_bf16(kf0, qf0, z, 0,0,0);
            s[jt] = __builtin_amdgcn_mfma_f32_16x16x32_bf16(kf1, qf1, s[jt], 0,0,0);
        }
        // ---- V frags
        bf16x8 vf[4][2];
        #pragma unroll
        for (int dt = 0; dt < 4; ++dt) {
            vf[dt][0] = *(const bf16x8*)(&Vt[dt*16 + r][g*8]);
            vf[dt][1] = *(const bf16x8*)(&Vt[dt*16 + r][32 + g*8]);
        }
        // ---- softmax (lane-local, defer-max)
        float mx = fmaxf(fmaxf(fmaxf(s[0][0], s[0][1]), fmaxf(s[0][2], s[0][3])),
                         fmaxf(fmaxf(s[1][0], s[1][1]), fmaxf(s[1][2], s[1][3])));
        mx = fmaxf(mx, fmaxf(fmaxf(fmaxf(s[2][0], s[2][1]), fmaxf(s[2][2], s[2][3])),
                             fmaxf(fmaxf(s[3][0], s[3][1]), fmaxf(s[3][2], s[3][3]))));
        mx = fmaxf(mx, __shfl_xor(mx, 16));
        mx = fmaxf(mx, __shfl_xor(mx, 32));
        if (!__all(mx <= mr + DTHR)) {    // T13: rescale only on significant growth
            float mnew = fmaxf(mr, mx);
            float a = exp2f(SCALE2 * (mr - mnew));
            mr = mnew;
            lr *= a;
            #pragma unroll
            for (int dt = 0; dt < 4; ++dt) o[dt] *= a;
        }
        float cm = SCALE2 * mr;
        float ps = 0.f;
        #pragma unroll
        for (int jt = 0; jt < 4; ++jt) {
            float p0 = exp2f(fmaf(SCALE2, s[jt][0], -cm));
            float p1 = exp2f(fmaf(SCALE2, s[jt][1], -cm));
            float p2 = exp2f(fmaf(SCALE2, s[jt][2], -cm));
            float p3 = exp2f(fmaf(SCALE2, s[jt][3], -cm));
            ps += (p0 + p1) + (p2 + p3);
            uint2 wrd; wrd.x = cvtpk(p0, p1); wrd.y = cvtpk(p2, p3);
            *(uint2*)(prow + ((32*jt + 8*g) ^ rx)) = wrd;
        }
        ps += __shfl_xor(ps, 16);
        ps += __shfl_xor(ps, 32);
        lr += ps;
        // ---- PV
        bf16x8 pb0 = *(const bf16x8*)(prow + ((16*g) ^ rx));
        bf16x8 pb1 = *(const bf16x8*)(prow + ((64 + 16*g) ^ rx));
        #pragma unroll
        for (int dt = 0; dt < 4; ++dt) {
            o[dt] = __builtin_amdgcn_mfma_f32_16x16x32_bf16(vf[dt][0], pb0, o[dt], 0,0,0);
            o[dt] = __builtin_amdgcn_mfma_f32_16x16x32_bf16(vf[dt][1], pb1, o[dt], 0,0,0);
        }
        __syncthreads();
        if (more) {
            *(bf16x8*)(&Kl[skv][sd]) = kk0;
            *(bf16x8*)(&Kl[skv][sd + 8]) = kk1;
            #pragma unroll
            for (int i = 0; i < 4; ++i) {
                unsigned lo = (unsigned)((const unsigned short*)&vv0)[i]
                            | ((unsigned)((const unsigned short*)&vv1)[i] << 16);
                unsigned hi = (unsigned)((const unsigned short*)&vv2)[i]
                            | ((unsigned)((const unsigned short*)&vv3)[i] << 16);
                uint2 wrd; wrd.x = lo; wrd.y = hi;
                *(uint2*)(&Vt[vd + i][vkv]) = wrd;
            }
        }
    }
    // epilogue: lane (g,r) holds O[q=q0+r][d=dt*16+g*4+rg]
    float inv = 1.0f / lr;
    #pragma unroll
    for (int dt = 0; dt < 4; ++dt) {
        float4 v0;
        v0.x = o[dt][0]*inv; v0.y = o[dt][1]*inv;
        v0.z = o[dt][2]*inv; v0.w = o[dt][3]*inv;
        *(float4*)(out + (size_t)(b*NSEQ + q0 + r)*EDIM + h*HD + dt*16 + g*4) = v0;
    }
}

extern "C" void kernel_launch(void* const* d_in, const int* in_sizes, int n_in,
                              void* d_out, int out_size, void* d_ws, size_t ws_size,
                              hipStream_t stream) {
    const float* x  = (const float*)d_in[0];
    const float* w  = (const float*)d_in[1];
    const float* bq = (const float*)d_in[2];
    float* outp = (float*)d_out;
    char* ws = (char*)d_ws;
    short* Xb  = (short*)(ws);
    short* Wt  = (short*)(ws + 8388608);
    float* Bp  = (float*)(ws + 8388608 + 6291456);
    short* QKV = (short*)(ws + 8388608 + 6291456 + 16384);
    k_convert_x<<<dim3(2048), dim3(256), 0, stream>>>(x, Xb, (MTOT*EDIM)/4);
    k_transpose_w<<<dim3(16, 32), dim3(256), 0, stream>>>(w, Wt);
    k_perm_bias<<<dim3(12), dim3(256), 0, stream>>>(bq, Bp);
    k_qkv_gemm<<<dim3(32, 24), dim3(256), 0, stream>>>(Xb, Wt, Bp, QKV);
    k_attn<<<dim3(32, 16, 2), dim3(256), 0, stream>>>(QKV, outp);
}

// Round 9
// 194.346 us; speedup vs baseline: 1.1350x; 1.1350x over previous
//
#include <hip/hip_runtime.h>
#include <hip/hip_bf16.h>
#include <math.h>

// Problem constants (MultiheadAttention: B=2, N=2048, E=1024, H=16, hd=64)
#define EDIM 1024
#define N3E  3072
#define NSEQ 2048
#define NB   2
#define NH   16
#define HD   64
#define MTOT (NB*NSEQ)   // 4096

typedef __attribute__((ext_vector_type(8))) short bf16x8;
typedef __attribute__((ext_vector_type(4))) float f32x4;
typedef __attribute__((ext_vector_type(16))) float f32x16;

#define SCALE2 0.360673760222241f   // 0.25 * log2(e)
#define DTHR   16.0f                // defer-max threshold

__device__ __forceinline__ short f2bf(float f) {
    union { float f; unsigned u; } v; v.f = f;
    unsigned r = v.u + 0x7FFFu + ((v.u >> 16) & 1u);   // RNE
    return (short)(r >> 16);
}

__device__ __forceinline__ unsigned cvtpk(float lo, float hi) {
    unsigned r;
    asm("v_cvt_pk_bf16_f32 %0, %1, %2" : "=v"(r) : "v"(lo), "v"(hi));
    return r;
}

// v_permlane32_swap_b32 vdst, vsrc — S2 semantics: vdst lanes 32-63 <-> vsrc
// lanes 0-31 (vdst.lo and vsrc.hi kept). After pl32swap(a, b), per lane pair:
//   a = [lo: old a@lo, hi: old b@lo],  b = [lo: old a@hi, hi: old b@hi]
// (Round-7 tested the S1-consistent operand order and failed with P-permutation
//  error signature; this round tests the S2-consistent order.)
__device__ __forceinline__ void pl32swap(unsigned &a, unsigned &b) {
    asm volatile("v_permlane32_swap_b32 %0, %1" : "+v"(a), "+v"(b));
}

__device__ __forceinline__ void gload16(const void* g, void* l) {
    __builtin_amdgcn_global_load_lds(
        (const __attribute__((address_space(1))) unsigned int*)g,
        (__attribute__((address_space(3))) unsigned int*)l, 16, 0, 0);
}

// ---------- prep 1: x fp32 -> bf16 ----------
__global__ __launch_bounds__(256) void k_convert_x(const float* __restrict__ x,
                                                   short* __restrict__ xb, int n4) {
    int i = blockIdx.x * blockDim.x + threadIdx.x;
    int stride = gridDim.x * blockDim.x;
    for (; i < n4; i += stride) {
        float4 v = ((const float4*)x)[i];
        ushort4 o;
        o.x = (unsigned short)f2bf(v.x);
        o.y = (unsigned short)f2bf(v.y);
        o.z = (unsigned short)f2bf(v.z);
        o.w = (unsigned short)f2bf(v.w);
        ((ushort4*)xb)[i] = o;
    }
}

// ---------- prep 2: W[k][c] fp32 -> Wt[c'][k] bf16 ----------
__global__ __launch_bounds__(256) void k_transpose_w(const float* __restrict__ w,
                                                     short* __restrict__ wt) {
    __shared__ float T[96][68];
    int k0 = blockIdx.x * 64;
    int c0 = blockIdx.y * 96;
    int t = threadIdx.x;
    {
        int kr = t >> 2;
        int cb = (t & 3) * 24;
        const float* src = w + (size_t)(k0 + kr) * N3E + c0 + cb;
        #pragma unroll
        for (int i = 0; i < 24; i += 4) {
            float4 v = *(const float4*)(src + i);
            T[cb + i + 0][kr] = v.x;
            T[cb + i + 1][kr] = v.y;
            T[cb + i + 2][kr] = v.z;
            T[cb + i + 3][kr] = v.w;
        }
    }
    __syncthreads();
    int kk = (t & 7) * 8;
    #pragma unroll
    for (int p = 0; p < 3; ++p) {
        int cc = p * 32 + (t >> 3);
        int ca = c0 + cc;
        int e = ca / 48, h = (ca % 48) / 3, q = ca % 3;
        int cp = q * 1024 + h * 64 + e;
        bf16x8 o;
        #pragma unroll
        for (int j = 0; j < 8; ++j) o[j] = f2bf(T[cc][kk + j]);
        *(bf16x8*)(wt + (size_t)cp * EDIM + k0 + kk) = o;
    }
}

// ---------- prep 3: bias permute ----------
__global__ void k_perm_bias(const float* __restrict__ b, float* __restrict__ bp) {
    int c = blockIdx.x * 256 + threadIdx.x;
    if (c >= N3E) return;
    int e = c / 48, h = (c % 48) / 3, q = c % 3;
    bp[q * 1024 + h * 64 + e] = b[c];
}

// ---------- QKV GEMM: 2-phase dbuf + global_load_lds(16B) + XCD swizzle ----------
// (round-5-proven version: passed absmax 0.0234)
__global__ __launch_bounds__(256) void k_qkv_gemm(const short* __restrict__ xb,
        const short* __restrict__ wt, const float* __restrict__ bp,
        short* __restrict__ qkv) {
    __shared__ short Al[2][128][32];
    __shared__ short Bl[2][128][32];
    int t = threadIdx.x, lane = t & 63, wv = t >> 6;
    int g = lane >> 4, r = lane & 15;
    int wr = wv >> 1, wc = wv & 1;
    // XCD-chunked swizzle: 768 blocks = 8 XCDs x 96
    int flat = blockIdx.y * 32 + blockIdx.x;
    int sw = (flat & 7) * 96 + (flat >> 3);
    int m0 = (sw & 31) * 128, n0 = (sw >> 5) * 128;
    int srow = wv * 32 + (lane >> 2);
    int scol = (lane & 3) * 8;
    const short* ga0 = xb + (size_t)(m0 + srow) * EDIM + scol;
    const short* ga1 = ga0 + (size_t)16 * EDIM;
    const short* gb0 = wt + (size_t)(n0 + srow) * EDIM + scol;
    const short* gb1 = gb0 + (size_t)16 * EDIM;
    char* laA = (char*)(&Al[0][0][0]) + wv * 2048;
    char* laB = (char*)(&Bl[0][0][0]) + wv * 2048;
    f32x4 acc[4][4] = {};
    gload16(ga0, laA);
    gload16(ga1, laA + 1024);
    gload16(gb0, laB);
    gload16(gb1, laB + 1024);
    __syncthreads();
    for (int step = 0; step < 32; ++step) {
        if (step < 31) {   // issue next K-step into the other buffer BEFORE compute
            int nk = (step + 1) * 32;
            int bo = ((step + 1) & 1) * 8192;
            gload16(ga0 + nk, laA + bo);
            gload16(ga1 + nk, laA + bo + 1024);
            gload16(gb0 + nk, laB + bo);
            gload16(gb1 + nk, laB + bo + 1024);
        }
        int cb = step & 1;
        bf16x8 af[4], bfr[4];
        #pragma unroll
        for (int mt = 0; mt < 4; ++mt)
            af[mt] = *(const bf16x8*)(&Al[cb][wr*64 + mt*16 + r][g*8]);
        #pragma unroll
        for (int nt = 0; nt < 4; ++nt)
            bfr[nt] = *(const bf16x8*)(&Bl[cb][wc*64 + nt*16 + r][g*8]);
        #pragma unroll
        for (int mt = 0; mt < 4; ++mt)
            #pragma unroll
            for (int nt = 0; nt < 4; ++nt)
                acc[mt][nt] = __builtin_amdgcn_mfma_f32_16x16x32_bf16(
                                  af[mt], bfr[nt], acc[mt][nt], 0, 0, 0);
        __syncthreads();   // drains vmcnt(0): next-buf loads had the MFMA phase to land
    }
    #pragma unroll
    for (int nt = 0; nt < 4; ++nt) {
        int cp = n0 + wc*64 + nt*16 + r;
        float bias = bp[cp];
        int q = cp >> 10, h = (cp >> 6) & 15, e = cp & 63;
        #pragma unroll
        for (int mt = 0; mt < 4; ++mt) {
            #pragma unroll
            for (int rg = 0; rg < 4; ++rg) {
                int m = m0 + wr*64 + mt*16 + g*4 + rg;
                int bb = m >> 11, n = m & 2047;
                qkv[((((size_t)q*NB + bb)*NH + h)*NSEQ + n)*HD + e] =
                    f2bf(acc[mt][nt][rg] + bias);
            }
        }
    }
}

// ---------- flash attention: 32x32x16 MFMA, P in-register via permlane32_swap ----------
// 4 waves x 32 q-rows (q-block 128), KVBLK=64, grid (16,16,2)=512 blocks.
// S^T = mfma(K, Q): lane(cq,hf) holds S[q=cq][kv=(e&3)+8(e>>2)+4hf (+32 for s1)].
// PV B-frag per kv-slab m: lane needs P[kv=16m+8hf+j][q=cq]:
//   u0 = [lo: pa0@lo | hi: pa2@lo]   u2 = [lo: pa0@hi | hi: pa2@hi]
// With S2 semantics, pl32swap(w0, w2) delivers exactly {w0=u0, w2=u2}.
__global__ __launch_bounds__(256) void k_attn(const short* __restrict__ qkv,
                                              float* __restrict__ out) {
    __shared__ short Kl[64][68];      // [kv][d]
    __shared__ short Vt[64][68];      // [d][kv]
    int t = threadIdx.x, lane = t & 63, wv = t >> 6;
    int cq = lane & 31, hf = lane >> 5;
    int qb = blockIdx.x, hd = blockIdx.y, b = blockIdx.z;
    const size_t HS = (size_t)NSEQ * HD;
    const short* Qp = qkv + ((size_t)(0*NB + b)*NH + hd) * HS;
    const short* Kp = qkv + ((size_t)(1*NB + b)*NH + hd) * HS;
    const short* Vp = qkv + ((size_t)(2*NB + b)*NH + hd) * HS;
    int q0 = qb * 128 + wv * 32;
    bf16x8 qf[4];
    #pragma unroll
    for (int ks = 0; ks < 4; ++ks)
        qf[ks] = *(const bf16x8*)(Qp + (size_t)(q0 + cq)*HD + 16*ks + 8*hf);
    f32x16 o0 = {}, o1 = {};          // O^T: d 0..31 / 32..63, col q = cq
    float mr = -3.0e38f, lr = 0.f;
    int skv = t >> 2, sd = (t & 3) * 16;          // K staging
    int vkv = (t >> 4) * 4, vd = (t & 15) * 4;    // V staging (4kv x 4d / lane)
    bf16x8 kk0, kk1; ushort4 vv0, vv1, vv2, vv3;
    const short* Kst = Kp + (size_t)skv * HD + sd;
    const short* Vst = Vp + (size_t)vkv * HD + vd;
    kk0 = *(const bf16x8*)(Kst);
    kk1 = *(const bf16x8*)(Kst + 8);
    vv0 = *(const ushort4*)(Vst);
    vv1 = *(const ushort4*)(Vst + HD);
    vv2 = *(const ushort4*)(Vst + 2*HD);
    vv3 = *(const ushort4*)(Vst + 3*HD);
    {
        *(bf16x8*)(&Kl[skv][sd]) = kk0;
        *(bf16x8*)(&Kl[skv][sd + 8]) = kk1;
        #pragma unroll
        for (int i = 0; i < 4; ++i) {
            unsigned lo = (unsigned)((const unsigned short*)&vv0)[i]
                        | ((unsigned)((const unsigned short*)&vv1)[i] << 16);
            unsigned hi = (unsigned)((const unsigned short*)&vv2)[i]
                        | ((unsigned)((const unsigned short*)&vv3)[i] << 16);
            uint2 wrd; wrd.x = lo; wrd.y = hi;
            *(uint2*)(&Vt[vd + i][vkv]) = wrd;
        }
    }
    for (int kt = 0; kt < NSEQ; kt += 64) {
        __syncthreads();
        bool more = (kt + 64) < NSEQ;
        if (more) {   // T14: next tile's global loads issued before compute
            kk0 = *(const bf16x8*)(Kst + (size_t)(kt + 64) * HD);
            kk1 = *(const bf16x8*)(Kst + (size_t)(kt + 64) * HD + 8);
            vv0 = *(const ushort4*)(Vst + (size_t)(kt + 64) * HD);
            vv1 = *(const ushort4*)(Vst + (size_t)(kt + 65) * HD);
            vv2 = *(const ushort4*)(Vst + (size_t)(kt + 66) * HD);
            vv3 = *(const ushort4*)(Vst + (size_t)(kt + 67) * HD);
        }
        // ---- QK^T: S^T tiles (kv 0..31 -> s0, 32..63 -> s1)
        f32x16 s0 = {}, s1 = {};
        #pragma unroll
        for (int ks = 0; ks < 4; ++ks) {
            bf16x8 kf0 = *(const bf16x8*)(&Kl[cq][16*ks + 8*hf]);
            bf16x8 kf1 = *(const bf16x8*)(&Kl[32 + cq][16*ks + 8*hf]);
            s0 = __builtin_amdgcn_mfma_f32_32x32x16_bf16(kf0, qf[ks], s0, 0, 0, 0);
            s1 = __builtin_amdgcn_mfma_f32_32x32x16_bf16(kf1, qf[ks], s1, 0, 0, 0);
        }
        // ---- V^T frags (A-operand for PV): vf[m] covers kv slab [16m,16m+16)
        bf16x8 vf0[4], vf1[4];
        #pragma unroll
        for (int m = 0; m < 4; ++m) {
            vf0[m] = *(const bf16x8*)(&Vt[cq][16*m + 8*hf]);
            vf1[m] = *(const bf16x8*)(&Vt[32 + cq][16*m + 8*hf]);
        }
        // ---- softmax (row q = cq split across lane pair l, l+32)
        float mx = s0[0];
        #pragma unroll
        for (int e = 1; e < 16; ++e) mx = fmaxf(mx, s0[e]);
        #pragma unroll
        for (int e = 0; e < 16; ++e) mx = fmaxf(mx, s1[e]);
        mx = fmaxf(mx, __shfl_xor(mx, 32));
        if (!__all(mx <= mr + DTHR)) {    // T13 defer-max
            float mnew = fmaxf(mr, mx);
            float a = exp2f(SCALE2 * (mr - mnew));
            mr = mnew; lr *= a;
            #pragma unroll
            for (int e = 0; e < 16; ++e) { o0[e] *= a; o1[e] *= a; }
        }
        float cm = SCALE2 * mr;
        float ps = 0.f;
        unsigned pa[8], pb[8];
        #pragma unroll
        for (int i = 0; i < 8; ++i) {
            float x0 = exp2f(fmaf(SCALE2, s0[2*i],   -cm));
            float x1 = exp2f(fmaf(SCALE2, s0[2*i+1], -cm));
            float y0 = exp2f(fmaf(SCALE2, s1[2*i],   -cm));
            float y1 = exp2f(fmaf(SCALE2, s1[2*i+1], -cm));
            ps += (x0 + x1) + (y0 + y1);
            pa[i] = cvtpk(x0, x1);
            pb[i] = cvtpk(y0, y1);
        }
        ps += __shfl_xor(ps, 32);
        lr += ps;
        // ---- PV: assemble B-frag per kv slab via 2 permlane32_swap, no LDS
        #pragma unroll
        for (int m = 0; m < 4; ++m) {
            int mp = m & 1;
            unsigned w0, w1, w2, w3;
            if (m < 2) { w0 = pa[4*mp]; w1 = pa[4*mp+1]; w2 = pa[4*mp+2]; w3 = pa[4*mp+3]; }
            else       { w0 = pb[4*mp]; w1 = pb[4*mp+1]; w2 = pb[4*mp+2]; w3 = pb[4*mp+3]; }
            pl32swap(w0, w2);   // S2: w0 -> [pa0@lo | pa2@lo], w2 -> [pa0@hi | pa2@hi]
            pl32swap(w1, w3);
            union { unsigned u[4]; bf16x8 v; } pu;
            pu.u[0] = w0; pu.u[1] = w1; pu.u[2] = w2; pu.u[3] = w3;
            o0 = __builtin_amdgcn_mfma_f32_32x32x16_bf16(vf0[m], pu.v, o0, 0, 0, 0);
            o1 = __builtin_amdgcn_mfma_f32_32x32x16_bf16(vf1[m], pu.v, o1, 0, 0, 0);
        }
        __syncthreads();
        if (more) {
            *(bf16x8*)(&Kl[skv][sd]) = kk0;
            *(bf16x8*)(&Kl[skv][sd + 8]) = kk1;
            #pragma unroll
            for (int i = 0; i < 4; ++i) {
                unsigned lo = (unsigned)((const unsigned short*)&vv0)[i]
                            | ((unsigned)((const unsigned short*)&vv1)[i] << 16);
                unsigned hi = (unsigned)((const unsigned short*)&vv2)[i]
                            | ((unsigned)((const unsigned short*)&vv3)[i] << 16);
                uint2 wrd; wrd.x = lo; wrd.y = hi;
                *(uint2*)(&Vt[vd + i][vkv]) = wrd;
            }
        }
    }
    // epilogue: lane (cq,hf) holds O^T[d][q=q0+cq]; d = (e&3)+8*(e>>2)+4hf+32*dt
    float inv = 1.0f / lr;
    float* dst = out + (size_t)(b*NSEQ + q0 + cq)*EDIM + hd*HD;
    #pragma unroll
    for (int rq = 0; rq < 4; ++rq) {
        float4 v0, v1;
        v0.x = o0[4*rq+0]*inv; v0.y = o0[4*rq+1]*inv;
        v0.z = o0[4*rq+2]*inv; v0.w = o0[4*rq+3]*inv;
        v1.x = o1[4*rq+0]*inv; v1.y = o1[4*rq+1]*inv;
        v1.z = o1[4*rq+2]*inv; v1.w = o1[4*rq+3]*inv;
        *(float4*)(dst + 8*rq + 4*hf)      = v0;
        *(float4*)(dst + 8*rq + 4*hf + 32) = v1;
    }
}

extern "C" void kernel_launch(void* const* d_in, const int* in_sizes, int n_in,
                              void* d_out, int out_size, void* d_ws, size_t ws_size,
                              hipStream_t stream) {
    const float* x  = (const float*)d_in[0];
    const float* w  = (const float*)d_in[1];
    const float* bq = (const float*)d_in[2];
    float* outp = (float*)d_out;
    char* ws = (char*)d_ws;
    short* Xb  = (short*)(ws);
    short* Wt  = (short*)(ws + 8388608);
    float* Bp  = (float*)(ws + 8388608 + 6291456);
    short* QKV = (short*)(ws + 8388608 + 6291456 + 16384);
    k_convert_x<<<dim3(2048), dim3(256), 0, stream>>>(x, Xb, (MTOT*EDIM)/4);
    k_transpose_w<<<dim3(16, 32), dim3(256), 0, stream>>>(w, Wt);
    k_perm_bias<<<dim3(12), dim3(256), 0, stream>>>(bq, Bp);
    k_qkv_gemm<<<dim3(32, 24), dim3(256), 0, stream>>>(Xb, Wt, Bp, QKV);
    k_attn<<<dim3(16, 16, 2), dim3(256), 0, stream>>>(QKV, outp);
}